// Round 10
// baseline (239.925 us; speedup 1.0000x reference)
//
#include <hip/hip_runtime.h>
#include <hip/hip_bf16.h>

#define DIN 4096
#define DOUT 4096
#define NROWS 8192  // B*S = 4*2048

typedef int i32x4 __attribute__((ext_vector_type(4)));

// ---------------- block-level absmax reduce (4 waves, 256 threads) -------------
__device__ __forceinline__ float block_absmax(float m, float* red) {
  #pragma unroll
  for (int off = 32; off > 0; off >>= 1)
    m = fmaxf(m, __shfl_down(m, off));
  const int tid = threadIdx.x;
  if ((tid & 63) == 0) red[tid >> 6] = m;
  __syncthreads();
  return fmaxf(fmaxf(red[0], red[1]), fmaxf(red[2], red[3]));
}

// ---------------- kernel 1: fused FWHT+quant (rows) / weight quant (rows) ------
__global__ __launch_bounds__(256) void fused_quant_kernel(
    const float* __restrict__ in, const float* __restrict__ w,
    char* __restrict__ qx, char* __restrict__ qw,
    float* __restrict__ sx, float* __restrict__ sw) {
  __shared__ float lds[4352];
  __shared__ float red[4];
  const int tid = threadIdx.x;

  if (blockIdx.x < NROWS) {
    const size_t row = blockIdx.x;
    const int th = tid >> 4, tl = tid & 15;
    float v[16];
    const float4* src = (const float4*)(in + row * DIN);
    #pragma unroll
    for (int k = 0; k < 4; ++k) {
      float4 f = src[tid * 4 + k];
      v[4 * k + 0] = f.x; v[4 * k + 1] = f.y;
      v[4 * k + 2] = f.z; v[4 * k + 3] = f.w;
    }
    #pragma unroll
    for (int hb = 1; hb < 16; hb <<= 1)
      #pragma unroll
      for (int j = 0; j < 16; ++j)
        if (!(j & hb)) {
          float a0 = v[j], b0 = v[j | hb];
          v[j] = a0 + b0; v[j | hb] = a0 - b0;
        }
    #pragma unroll
    for (int j = 0; j < 16; ++j) lds[17 * tid + j] = v[j];
    __syncthreads();
    #pragma unroll
    for (int j = 0; j < 16; ++j) v[j] = lds[272 * th + 17 * j + tl];
    #pragma unroll
    for (int hb = 1; hb < 16; hb <<= 1)
      #pragma unroll
      for (int j = 0; j < 16; ++j)
        if (!(j & hb)) {
          float a0 = v[j], b0 = v[j | hb];
          v[j] = a0 + b0; v[j | hb] = a0 - b0;
        }
    #pragma unroll
    for (int j = 0; j < 16; ++j) lds[272 * th + 17 * j + tl] = v[j];
    __syncthreads();
    #pragma unroll
    for (int j = 0; j < 16; ++j) v[j] = lds[272 * j + 17 * th + tl];
    #pragma unroll
    for (int hb = 1; hb < 16; hb <<= 1)
      #pragma unroll
      for (int j = 0; j < 16; ++j)
        if (!(j & hb)) {
          float a0 = v[j], b0 = v[j | hb];
          v[j] = a0 + b0; v[j | hb] = a0 - b0;
        }
    float m = 0.0f;
    #pragma unroll
    for (int j = 0; j < 16; ++j) m = fmaxf(m, fabsf(v[j]));
    #pragma unroll
    for (int j = 0; j < 16; ++j) lds[272 * j + 17 * th + tl] = v[j];
    float mx = block_absmax(m, red) * 0.015625f;  // 1/sqrt(4096) exact
    float scale = fmaxf(mx / 127.0f, 1e-8f);
    if (tid == 0) sx[row] = scale;
    const float rs = 1.0f / scale;
    char pk[16];
    #pragma unroll
    for (int j = 0; j < 16; ++j) {
      float q = fminf(fmaxf(rintf((lds[17 * tid + j] * 0.015625f) * rs), -127.f),
                      127.f);
      pk[j] = (char)q;
    }
    *(int4*)(qx + row * DIN + (size_t)tid * 16) = *(const int4*)pk;
  } else {
    const size_t row = blockIdx.x - NROWS;
    const float4* src = (const float4*)(w + row * DIN);
    float4* b4 = (float4*)lds;
    float m = 0.0f;
    for (int i = tid; i < DIN / 4; i += 256) {
      float4 v = src[i];
      b4[i] = v;
      m = fmaxf(m, fmaxf(fmaxf(fabsf(v.x), fabsf(v.y)),
                         fmaxf(fabsf(v.z), fabsf(v.w))));
    }
    float mx = block_absmax(m, red);
    float scale = fmaxf(mx / 7.0f, 1e-8f);
    if (tid == 0) sw[row] = scale;
    char* dst = qw + row * DIN;
    const float rs = 1.0f / scale;
    for (int i0 = tid * 4; i0 < DIN; i0 += 1024) {
      char4 pk;
      float q0 = fminf(fmaxf(rintf(lds[i0 + 0] * rs), -7.f), 7.f);
      float q1 = fminf(fmaxf(rintf(lds[i0 + 1] * rs), -7.f), 7.f);
      float q2 = fminf(fmaxf(rintf(lds[i0 + 2] * rs), -7.f), 7.f);
      float q3 = fminf(fmaxf(rintf(lds[i0 + 3] * rs), -7.f), 7.f);
      pk.x = (char)q0; pk.y = (char)q1; pk.z = (char)q2; pk.w = (char)q3;
      *(char4*)(dst + i0) = pk;
    }
  }
}

// ---------------- kernel 3: i8 MFMA GEMM, 256x128 tile, 2 blocks/CU ------------
// 8 waves (4 row-groups x 2 col-groups), BK=64 (64 B/row), 8 phases / 2 K-tiles.
// LDS 48 KiB: As[2][256][64] @0, Bs[2][128][64] @32768 -> 2 resident blocks/CU;
// unified regs ~110 (acc 64) -> 16 waves/CU. Independent blocks fill each
// other's barrier/drain stalls (m97 mechanism at 8-phase quality).
// Swizzle: 16B-slot ^= ((row>>1)&3) on pre-swizzled global src + ds_read
// (64B rows: balanced over all 32 banks, conflict-free). Counted vmcnt(2) at
// ph4/ph8 drains exactly the completing buffer's 3 stage-units.
__global__ __launch_bounds__(512, 4) void gemm_kernel(
    const char* __restrict__ A,   // [NROWS][DIN] q_x int8
    const char* __restrict__ Bt,  // [DOUT][DIN]  q_w int8
    const float* __restrict__ sx, const float* __restrict__ sw,
    const float* __restrict__ bias, float* __restrict__ out) {
  __shared__ char lds[49152];
  const int tid = threadIdx.x;
  const int lane = tid & 63;
  const int wid = tid >> 6;
  const int wr = wid >> 1;  // 0..3 (16-row group within each 64-row slab)
  const int wc = wid & 1;   // 0..1 (64-col group)
  int bid = blockIdx.x;                     // 1024 blocks
  int swz = (bid & 7) * 128 + (bid >> 3);   // bijective XCD swizzle (1024%8==0)
  const size_t row0 = (size_t)(swz >> 5) * 256;  // 32 M-tiles
  const size_t col0 = (size_t)(swz & 31) * 128;  // 32 N-tiles
  const int g16 = lane >> 4;  // k-group (16B) within the 64B K-tile

  i32x4 acc[4][4] = {};  // [slab q][nn]
  i32x4 fb[4];           // [nn] B frags, persist over a 4-phase group
  i32x4 fa;              // per-phase A frag

// one 8KB stage unit: 512 thr x 16B; chunk=wid (1KB), row rr=wid*16+(lane>>2),
// source slot pre-swizzled so LDS[row][slot] = global[row][slot ^ ((row>>1)&3)]
#define STAGE_UNIT(MAT, GROW0, KT, LBASE)                                     \
  {                                                                           \
    int rr = wid * 16 + (lane >> 2);                                          \
    int cc = (KT) * 64 + ((((lane & 3) ^ ((rr >> 1) & 3))) << 4);             \
    const char* src = (MAT) + ((GROW0) + rr) * (size_t)DIN + cc;              \
    __builtin_amdgcn_global_load_lds(                                         \
        (const __attribute__((address_space(1))) void*)src,                   \
        (__attribute__((address_space(3))) void*)(lds + (LBASE) +             \
                                                  wid * 1024),                \
        16, 0, 0);                                                            \
  }
#define STAGE_A(P, HALF, KT) \
  STAGE_UNIT(A, row0 + (HALF) * 128, KT, (P) * 16384 + (HALF) * 8192)
#define STAGE_B(P, KT) STAGE_UNIT(Bt, col0, KT, 32768 + (P) * 8192)

#define DS_FA(Q, P)                                                           \
  {                                                                           \
    int ar = (Q) * 64 + wr * 16 + (lane & 15);                                \
    fa = *(const i32x4*)(lds + (P) * 16384 + ar * 64 +                        \
                         ((g16 ^ ((ar >> 1) & 3)) << 4));                     \
  }
#define DS_FB(P)                                                              \
  {                                                                           \
    _Pragma("unroll")                                                         \
    for (int nn = 0; nn < 4; ++nn) {                                          \
      int br = wc * 64 + nn * 16 + (lane & 15);                               \
      fb[nn] = *(const i32x4*)(lds + 32768 + (P) * 8192 + br * 64 +           \
                               ((g16 ^ ((br >> 1) & 3)) << 4));               \
    }                                                                         \
  }
#define MFMA4(Q)                                                              \
  {                                                                           \
    __builtin_amdgcn_s_setprio(1);                                            \
    _Pragma("unroll")                                                         \
    for (int nn = 0; nn < 4; ++nn)                                            \
      acc[Q][nn] = __builtin_amdgcn_mfma_i32_16x16x64_i8(                     \
          fa, fb[nn], acc[Q][nn], 0, 0, 0);                                   \
    __builtin_amdgcn_s_setprio(0);                                            \
  }
#define BAR() __builtin_amdgcn_s_barrier()
#define WAIT_LGKM0() asm volatile("s_waitcnt lgkmcnt(0)" ::: "memory")

  // -------- prologue: buf0 <- kt0 {B,A0,A1}; buf1 <- kt1 {B,A0}
  STAGE_B(0, 0); STAGE_A(0, 0, 0); STAGE_A(0, 1, 0);
  STAGE_B(1, 1); STAGE_A(1, 0, 1);
  asm volatile("s_waitcnt vmcnt(2)" ::: "memory");  // buf0 fully landed
  BAR();

  #pragma unroll 1
  for (int i = 0; i < 32; ++i) {
    const int a = 2 * i, b = 2 * i + 1;
    const bool nl = (i < 31);
    // ---- ph1: slab0 of buf0 (+fb); stage buf1.A1(b) (read last at prev ph8)
    DS_FA(0, 0); DS_FB(0);
    STAGE_A(1, 1, b);
    BAR(); WAIT_LGKM0();
    MFMA4(0);
    BAR();
    // ---- ph2: slab1; stage buf0.B(a+2) (B read only at ph1)
    DS_FA(1, 0);
    if (nl) STAGE_B(0, a + 2);
    BAR(); WAIT_LGKM0();
    MFMA4(1);
    BAR();
    // ---- ph3: slab2; stage buf0.A0(a+2) (rows 0-127 read ph1/ph2)
    DS_FA(2, 0);
    if (nl) STAGE_A(0, 0, a + 2);
    BAR(); WAIT_LGKM0();
    MFMA4(2);
    BAR();
    // ---- ph4: slab3; vmcnt(2) -> buf1(b) fully landed before ph5 reads
    DS_FA(3, 0);
    BAR(); WAIT_LGKM0();
    MFMA4(3);
    if (nl) { asm volatile("s_waitcnt vmcnt(2)" ::: "memory"); }
    else    { asm volatile("s_waitcnt vmcnt(0)" ::: "memory"); }
    BAR();
    // ---- ph5: slab0 of buf1 (+fb); stage buf0.A1(a+2) (rows 128-255 read ph3/4)
    DS_FA(0, 1); DS_FB(1);
    if (nl) STAGE_A(0, 1, a + 2);
    BAR(); WAIT_LGKM0();
    MFMA4(0);
    BAR();
    // ---- ph6: slab1; stage buf1.B(b+2)
    DS_FA(1, 1);
    if (nl) STAGE_B(1, b + 2);
    BAR(); WAIT_LGKM0();
    MFMA4(1);
    BAR();
    // ---- ph7: slab2; stage buf1.A0(b+2)
    DS_FA(2, 1);
    if (nl) STAGE_A(1, 0, b + 2);
    BAR(); WAIT_LGKM0();
    MFMA4(2);
    BAR();
    // ---- ph8: slab3; vmcnt(2) -> buf0(a+2) fully landed for next ph1
    DS_FA(3, 1);
    BAR(); WAIT_LGKM0();
    MFMA4(3);
    if (nl) { asm volatile("s_waitcnt vmcnt(2)" ::: "memory"); }
    BAR();
  }

  // -------- epilogue (R2-proven orientation): D col = lane&15,
  // row = 4*(lane>>4)+j within each (q, wr) 16-row group.
  #pragma unroll
  for (int q = 0; q < 4; ++q) {
    #pragma unroll
    for (int nn = 0; nn < 4; ++nn) {
      size_t gc = col0 + wc * 64 + nn * 16 + (lane & 15);
      float swc = sw[gc], bc = bias[gc];
      #pragma unroll
      for (int j = 0; j < 4; ++j) {
        size_t gr = row0 + q * 64 + wr * 16 + (g16 << 2) + j;
        out[gr * DOUT + gc] = (float)acc[q][nn][j] * (sx[gr] * swc) + bc;
      }
    }
  }
#undef STAGE_UNIT
#undef STAGE_A
#undef STAGE_B
#undef DS_FA
#undef DS_FB
#undef MFMA4
#undef BAR
#undef WAIT_LGKM0
}

// ---------------- kernel 4: per-token 8-bit fake quant of output, in place ----
__global__ __launch_bounds__(256) void rowquant_kernel(float* __restrict__ out) {
  __shared__ float red[4];
  const int tid = threadIdx.x;
  const size_t row = blockIdx.x;
  float4* g4 = (float4*)(out + row * DOUT);
  float4 v[4];
  float m = 0.0f;
  #pragma unroll
  for (int k = 0; k < 4; ++k) {
    v[k] = g4[tid + k * 256];
    m = fmaxf(m, fmaxf(fmaxf(fabsf(v[k].x), fabsf(v[k].y)),
                       fmaxf(fabsf(v[k].z), fabsf(v[k].w))));
  }
  float mx = block_absmax(m, red);
  float scale = fmaxf(mx / 127.0f, 1e-8f);
  #pragma unroll
  for (int k = 0; k < 4; ++k) {
    float4 w = v[k];
    w.x = fminf(fmaxf(rintf(w.x / scale), -127.0f), 127.0f) * scale;
    w.y = fminf(fmaxf(rintf(w.y / scale), -127.0f), 127.0f) * scale;
    w.z = fminf(fmaxf(rintf(w.z / scale), -127.0f), 127.0f) * scale;
    w.w = fminf(fmaxf(rintf(w.w / scale), -127.0f), 127.0f) * scale;
    g4[tid + k * 256] = w;
  }
}

extern "C" void kernel_launch(void* const* d_in, const int* in_sizes, int n_in,
                              void* d_out, int out_size, void* d_ws, size_t ws_size,
                              hipStream_t stream) {
  (void)in_sizes; (void)n_in; (void)out_size; (void)ws_size;
  const float* input = (const float*)d_in[0];
  const float* weight = (const float*)d_in[1];
  const float* bias = (const float*)d_in[2];
  float* out = (float*)d_out;
  char* ws = (char*)d_ws;
  char* qx = ws;
  char* qw = ws + ((size_t)32 << 20);
  float* sx = (float*)(ws + ((size_t)48 << 20));
  float* sw = (float*)(ws + ((size_t)48 << 20) + ((size_t)32 << 10));

  fused_quant_kernel<<<NROWS + DOUT, 256, 0, stream>>>(input, weight, qx, qw,
                                                       sx, sw);
  gemm_kernel<<<1024, 512, 0, stream>>>(qx, qw, sx, sw, bias, out);
  rowquant_kernel<<<NROWS, 256, 0, stream>>>(out);
}